// Round 3
// baseline (1874.256 us; speedup 1.0000x reference)
//
#include <hip/hip_runtime.h>
#include <stdint.h>

typedef unsigned short u16;
typedef unsigned int   u32;

// ---------- bf16 helpers (raw ushort representation) ----------
__device__ __forceinline__ float b2f(u16 u) { return __uint_as_float(((u32)u) << 16); }
__device__ __forceinline__ float blo(u32 u) { return __uint_as_float(u << 16); }
__device__ __forceinline__ float bhi(u32 u) { return __uint_as_float(u & 0xffff0000u); }
__device__ __forceinline__ u16 f2b(float f) {
    u32 x = __float_as_uint(f);
    u32 r = (x + 0x7fffu + ((x >> 16) & 1u)) >> 16;
    return (u16)r;
}

#define NB   4
#define IC   256
#define NPOS 4096
#define CH   64
#define HW   16384

// ======================================================================
// prep: transpose small weights (fp32 -> fp32)
// ======================================================================
__global__ __launch_bounds__(256) void prep_kernel(
    const float* __restrict__ wsw, const float* __restrict__ wcw,
    const float* __restrict__ m1w,
    float* __restrict__ wswT, float* __restrict__ wcwT, float* __restrict__ m1wT)
{
    int idx = blockIdx.x * 256 + threadIdx.x;
    if (idx < 4096) {
        int i = idx >> 6, c = idx & 63;
        wswT[i*64 + c] = wsw[c*64 + i];   // [i][c]: per-i rows contiguous
        wcwT[i*64 + c] = wcw[c*64 + i];
    }
    if (idx < 9216) {
        int o = idx & 15, ct = idx >> 4;
        int t = ct % 9, c = ct / 9;
        m1wT[idx] = m1w[(o*64 + c)*9 + t]; // [(c,t)][o]: 16 contiguous per tap
    }
}

// ======================================================================
// QKV: Q/K/V[n][o] = sum_i W[o][i]*x1[i][n] + bias   (bf16 out)
// ======================================================================
__global__ __launch_bounds__(256) void qkv_kernel(
    const float* __restrict__ x,
    const float* __restrict__ thw, const float* __restrict__ phw, const float* __restrict__ gw,
    const float* __restrict__ thb, const float* __restrict__ phb, const float* __restrict__ gb,
    u16* __restrict__ Q, u16* __restrict__ K, u16* __restrict__ V)
{
    const int n  = blockIdx.x * 256 + threadIdx.x;
    const int ob = blockIdx.y * 8;
    const int b  = blockIdx.z;
    const float* xp = x + (size_t)b * (IC*NPOS) + n;
    float aq[8], ak[8], av[8];
    #pragma unroll
    for (int j=0;j<8;j++){ aq[j]=0.f; ak[j]=0.f; av[j]=0.f; }
    #pragma unroll 4
    for (int i=0;i<256;i++){
        float xv = xp[(size_t)i*NPOS];
        #pragma unroll
        for (int j=0;j<8;j++){
            aq[j] = fmaf(thw[(ob+j)*256 + i], xv, aq[j]);
            ak[j] = fmaf(phw[(ob+j)*256 + i], xv, ak[j]);
            av[j] = fmaf(gw [(ob+j)*256 + i], xv, av[j]);
        }
    }
    size_t base = ((size_t)b*NPOS + n) * IC + ob;
    #pragma unroll
    for (int j=0;j<8;j++){
        Q[base + j] = f2b(aq[j] + thb[ob+j]);
        K[base + j] = f2b(ak[j] + phb[ob+j]);
        V[base + j] = f2b(av[j] + gb[ob+j]);
    }
}

// ======================================================================
// f_c[c][d] = sum_n Q[n][c]*K[n][d]   (per batch), fp32 out
// ======================================================================
__global__ __launch_bounds__(256) void fc_kernel(
    const u16* __restrict__ Q, const u16* __restrict__ K, float* __restrict__ fc)
{
    __shared__ __align__(16) u32 Qt[64*16];
    __shared__ __align__(16) u32 Kt[64*16];
    const int tid = threadIdx.x;
    const int c0 = blockIdx.x * 32, d0 = blockIdx.y * 32, b = blockIdx.z;
    const int tc = tid >> 4, td = tid & 15;
    float a00=0.f,a01=0.f,a10=0.f,a11=0.f;
    for (int nt=0; nt<64; nt++){
        int n0 = nt*64;
        __syncthreads();
        {
            int r = tid >> 2, cu = (tid & 3) * 4;
            *(uint4*)&Qt[r*16+cu] = *(const uint4*)(Q + ((size_t)(b*NPOS + n0 + r))*IC + c0 + cu*2);
            *(uint4*)&Kt[r*16+cu] = *(const uint4*)(K + ((size_t)(b*NPOS + n0 + r))*IC + d0 + cu*2);
        }
        __syncthreads();
        #pragma unroll 8
        for (int nn=0; nn<64; nn++){
            u32 qa = Qt[nn*16 + tc];
            u32 ka = Kt[nn*16 + td];
            float q0 = blo(qa), q1 = bhi(qa);
            float k0 = blo(ka), k1 = bhi(ka);
            a00 = fmaf(q0,k0,a00); a01 = fmaf(q0,k1,a01);
            a10 = fmaf(q1,k0,a10); a11 = fmaf(q1,k1,a11);
        }
    }
    float* fo = fc + (size_t)b*65536 + (size_t)(c0 + tc*2)*256 + d0 + td*2;
    fo[0] = a00; fo[1] = a01; fo[256] = a10; fo[257] = a11;
}

// ======================================================================
// row softmax over f_c (rows of 256)
// ======================================================================
__global__ __launch_bounds__(256) void softmax_fc_kernel(
    const float* __restrict__ fc, float* __restrict__ pc)
{
    __shared__ float red[8];
    const int tid = threadIdx.x;
    const int b = blockIdx.x >> 8, c = blockIdx.x & 255;
    float v = fc[(size_t)b*65536 + (size_t)c*256 + tid];
    float m = v;
    #pragma unroll
    for (int d=32; d>=1; d>>=1) m = fmaxf(m, __shfl_xor(m, d));
    if ((tid & 63) == 0) red[tid>>6] = m;
    __syncthreads();
    m = fmaxf(fmaxf(red[0],red[1]), fmaxf(red[2],red[3]));
    float e = __expf(v - m);
    float s = e;
    #pragma unroll
    for (int d=32; d>=1; d>>=1) s += __shfl_xor(s, d);
    if ((tid & 63) == 0) red[4 + (tid>>6)] = s;
    __syncthreads();
    s = red[4]+red[5]+red[6]+red[7];
    pc[(size_t)b*65536 + (size_t)c*256 + tid] = e / s;
}

// ======================================================================
// y_c[n][d] = sum_o V[n][o]*pc[o][d]  -> bf16, flat [n*256+d] == chw flat
// ======================================================================
__global__ __launch_bounds__(256) void yc_kernel(
    const u16* __restrict__ V, const float* __restrict__ pc, u16* __restrict__ ycb)
{
    __shared__ __align__(16) u32 Vt[64*20];   // stride 20 uints (pad)
    __shared__ __align__(16) float Pt[32*64];
    const int tid = threadIdx.x;
    const int n0 = blockIdx.x * 64, d0 = blockIdx.y * 64, b = blockIdx.z;
    const int tn = tid >> 4, td = tid & 15;
    float acc[4][4];
    #pragma unroll
    for (int j=0;j<4;j++)
        #pragma unroll
        for (int d=0;d<4;d++) acc[j][d]=0.f;
    for (int ot=0; ot<8; ot++){
        int o0 = ot*32;
        __syncthreads();
        {
            int r = tid >> 2, cu = (tid & 3) * 4;
            *(uint4*)&Vt[r*20+cu] = *(const uint4*)(V + ((size_t)(b*NPOS + n0 + r))*IC + o0 + cu*2);
            int r2 = tid >> 3, cf = (tid & 7) * 8;
            const float* ps = pc + (size_t)b*65536 + (size_t)(o0 + r2)*256 + d0 + cf;
            *(float4*)&Pt[r2*64+cf]   = *(const float4*)ps;
            *(float4*)&Pt[r2*64+cf+4] = *(const float4*)(ps+4);
        }
        __syncthreads();
        #pragma unroll 4
        for (int kk=0; kk<32; kk++){
            float4 pv = *(const float4*)&Pt[kk*64 + td*4];
            #pragma unroll
            for (int j=0;j<4;j++){
                u32 va = Vt[(tn*4+j)*20 + (kk>>1)];
                float vf = (kk & 1) ? bhi(va) : blo(va);
                acc[j][0] = fmaf(vf, pv.x, acc[j][0]);
                acc[j][1] = fmaf(vf, pv.y, acc[j][1]);
                acc[j][2] = fmaf(vf, pv.z, acc[j][2]);
                acc[j][3] = fmaf(vf, pv.w, acc[j][3]);
            }
        }
    }
    #pragma unroll
    for (int j=0;j<4;j++){
        u32 lo = (u32)f2b(acc[j][0]) | ((u32)f2b(acc[j][1]) << 16);
        u32 hi = (u32)f2b(acc[j][2]) | ((u32)f2b(acc[j][3]) << 16);
        *(uint2*)&ycb[((size_t)b*NPOS + n0 + tn*4 + j)*IC + d0 + td*4] = make_uint2(lo,hi);
    }
}

// ======================================================================
// Flash attention: O[n][o] = softmax_m(Q·K^T) @ V, written TRANSPOSED
// to ysT[b][o][n] (== chw flat). Bq=32, Bk=64, D=256.
// ======================================================================
#define KSTR 132   // uints per KV row (264 bf16, padded)

__global__ __launch_bounds__(256) void flash_kernel(
    const u16* __restrict__ Q, const u16* __restrict__ K, const u16* __restrict__ V,
    u16* __restrict__ ysT)
{
    __shared__ __align__(16) u32 Qs[32*128];     // 16 KB
    __shared__ __align__(16) u32 KVs[64*KSTR];   // 33 KB (K tile, then V tile, then O transpose)
    __shared__ __align__(16) float Ps[32*64];    // 8 KB
    const int tid = threadIdx.x;
    const int b  = blockIdx.y;
    const int n0 = blockIdx.x * 32;
    const int tq = tid >> 5, tk = tid & 31;

    {   // stage Q tile (persistent)
        int q = tid >> 3, cu = (tid & 7) * 16;
        const uint4* src = (const uint4*)(Q + ((size_t)(b*NPOS + n0 + q))*IC) + (cu >> 2);
        uint4* dst = (uint4*)&Qs[q*128 + cu];
        #pragma unroll
        for (int m=0;m<4;m++) dst[m] = src[m];
    }

    float acc[4][8];
    float mrow[4], lrow[4];
    #pragma unroll
    for (int j=0;j<4;j++){
        mrow[j] = -1e30f; lrow[j] = 0.f;
        #pragma unroll
        for (int o=0;o<8;o++) acc[j][o] = 0.f;
    }

    for (int kt=0; kt<64; kt++){
        const int m0 = kt*64;
        __syncthreads();
        {   // stage K tile
            int k = tid >> 2, cu = (tid & 3) * 32;
            const uint4* src = (const uint4*)(K + ((size_t)(b*NPOS + m0 + k))*IC) + (cu >> 2);
            uint4* dst = (uint4*)&KVs[k*KSTR + cu];
            #pragma unroll
            for (int m=0;m<8;m++) dst[m] = src[m];
        }
        __syncthreads();
        // ---- S = Q K^T  (each thread: 4 q rows x 2 k cols) ----
        float s[4][2];
        #pragma unroll
        for (int j=0;j<4;j++){ s[j][0]=0.f; s[j][1]=0.f; }
        #pragma unroll 2
        for (int cu=0; cu<128; cu+=4){
            uint4 k0 = *(const uint4*)&KVs[tk*KSTR + cu];
            uint4 k1 = *(const uint4*)&KVs[(tk+32)*KSTR + cu];
            float kf0[8] = {blo(k0.x),bhi(k0.x),blo(k0.y),bhi(k0.y),blo(k0.z),bhi(k0.z),blo(k0.w),bhi(k0.w)};
            float kf1[8] = {blo(k1.x),bhi(k1.x),blo(k1.y),bhi(k1.y),blo(k1.z),bhi(k1.z),blo(k1.w),bhi(k1.w)};
            #pragma unroll
            for (int j=0;j<4;j++){
                uint4 qq = *(const uint4*)&Qs[(tq*4+j)*128 + cu];
                float qf[8] = {blo(qq.x),bhi(qq.x),blo(qq.y),bhi(qq.y),blo(qq.z),bhi(qq.z),blo(qq.w),bhi(qq.w)};
                float t0 = s[j][0], t1 = s[j][1];
                #pragma unroll
                for (int e=0;e<8;e++){ t0 = fmaf(qf[e], kf0[e], t0); t1 = fmaf(qf[e], kf1[e], t1); }
                s[j][0]=t0; s[j][1]=t1;
            }
        }
        // ---- online softmax (row = 32 consecutive lanes) ----
        #pragma unroll
        for (int j=0;j<4;j++){
            float rm = fmaxf(s[j][0], s[j][1]);
            #pragma unroll
            for (int d=16; d>=1; d>>=1) rm = fmaxf(rm, __shfl_xor(rm, d));
            float mnew  = fmaxf(mrow[j], rm);
            float alpha = __expf(mrow[j] - mnew);
            float p0 = __expf(s[j][0] - mnew);
            float p1 = __expf(s[j][1] - mnew);
            float rs = p0 + p1;
            #pragma unroll
            for (int d=16; d>=1; d>>=1) rs += __shfl_xor(rs, d);
            lrow[j] = lrow[j]*alpha + rs;
            mrow[j] = mnew;
            #pragma unroll
            for (int o=0;o<8;o++) acc[j][o] *= alpha;
            Ps[(tq*4+j)*64 + tk]      = p0;
            Ps[(tq*4+j)*64 + tk + 32] = p1;
        }
        __syncthreads();
        {   // stage V tile (overwrites K tile)
            int k = tid >> 2, cu = (tid & 3) * 32;
            const uint4* src = (const uint4*)(V + ((size_t)(b*NPOS + m0 + k))*IC) + (cu >> 2);
            uint4* dst = (uint4*)&KVs[k*KSTR + cu];
            #pragma unroll
            for (int m=0;m<8;m++) dst[m] = src[m];
        }
        __syncthreads();
        // ---- O += P V  (each thread: 4 q rows x 8 o cols, o = tk*8..) ----
        #pragma unroll 2
        for (int k=0;k<64;k++){
            uint4 vv = *(const uint4*)&KVs[k*KSTR + tk*4];
            float vf[8] = {blo(vv.x),bhi(vv.x),blo(vv.y),bhi(vv.y),blo(vv.z),bhi(vv.z),blo(vv.w),bhi(vv.w)};
            #pragma unroll
            for (int j=0;j<4;j++){
                float p = Ps[(tq*4+j)*64 + k];
                #pragma unroll
                for (int o=0;o<8;o++) acc[j][o] = fmaf(p, vf[o], acc[j][o]);
            }
        }
    }
    // ---- epilogue: normalize, transpose via LDS, coalesced store ----
    __syncthreads();
    float* Ot = (float*)KVs;    // [256 o][stride 33]
    #pragma unroll
    for (int j=0;j<4;j++){
        float inv = 1.f / lrow[j];
        #pragma unroll
        for (int o=0;o<8;o++)
            Ot[(tk*8+o)*33 + tq*4 + j] = acc[j][o] * inv;
    }
    __syncthreads();
    {
        int lane = tid & 63, w = tid >> 6;
        int half = lane >> 5, q = lane & 31;
        u16* dst = ysT + (size_t)b*(IC*NPOS) + n0 + q;
        for (int it=0; it<32; it++){
            int o = w*64 + it*2 + half;
            dst[(size_t)o*NPOS] = f2b(Ot[o*33 + q]);
        }
    }
}

// ======================================================================
// z = x + gs*(Ws@y_s + Ws_b) + gc*(Wc@y_c + Wc_b)   (fp32 out to d_out)
// ======================================================================
__global__ __launch_bounds__(256) void z_kernel(
    const float* __restrict__ x, const u16* __restrict__ ysT, const u16* __restrict__ ycb,
    const float* __restrict__ wswT, const float* __restrict__ wcwT,
    const float* __restrict__ wsb, const float* __restrict__ wcb,
    const float* __restrict__ gs, const float* __restrict__ gc,
    float* __restrict__ zout)
{
    __shared__ __align__(16) float Wsl[64*32];
    __shared__ __align__(16) float Wcl[64*32];
    const int tid = threadIdx.x;
    const int p = blockIdx.x * 256 + tid;
    const int cbase = blockIdx.y * 32;
    const int b = blockIdx.z;
    {
        int i = tid >> 2, c8 = (tid & 3) * 8;
        const float* s1 = wswT + i*64 + cbase + c8;
        const float* s2 = wcwT + i*64 + cbase + c8;
        *(float4*)&Wsl[i*32 + c8]     = *(const float4*)s1;
        *(float4*)&Wsl[i*32 + c8 + 4] = *(const float4*)(s1+4);
        *(float4*)&Wcl[i*32 + c8]     = *(const float4*)s2;
        *(float4*)&Wcl[i*32 + c8 + 4] = *(const float4*)(s2+4);
    }
    __syncthreads();
    float as[32], ac[32];
    #pragma unroll
    for (int c=0;c<32;c++){ as[c]=0.f; ac[c]=0.f; }
    const u16* ysp = ysT + (size_t)b*(IC*NPOS) + p;
    const u16* ycp = ycb + (size_t)b*(IC*NPOS) + p;
    for (int i=0;i<64;i++){
        float ysv = b2f(ysp[(size_t)i*HW]);
        float ycv = b2f(ycp[(size_t)i*HW]);
        #pragma unroll
        for (int c=0;c<32;c++){
            as[c] = fmaf(Wsl[i*32+c], ysv, as[c]);
            ac[c] = fmaf(Wcl[i*32+c], ycv, ac[c]);
        }
    }
    float gsv = gs[0], gcv = gc[0];
    #pragma unroll
    for (int c=0;c<32;c++){
        int cg = cbase + c;
        float xv = x[((size_t)b*CH + cg)*HW + p];
        float zv = fmaf(gsv, as[c] + wsb[cg], xv);
        zv = fmaf(gcv, ac[c] + wcb[cg], zv);
        zout[((size_t)b*CH + cg)*HW + p] = zv;
    }
}

// ======================================================================
// conv3x3 (64->16) + ReLU   (reads fp32 z from d_out)
// ======================================================================
__global__ __launch_bounds__(256) void conv1_kernel(
    const float* __restrict__ z, const float* __restrict__ m1wT, const float* __restrict__ m1b,
    float* __restrict__ hmid)
{
    const int tid = threadIdx.x;
    const int p = blockIdx.x * 256 + tid;
    const int b = blockIdx.y;
    const int y = p >> 7, xx = p & 127;
    float acc[16];
    #pragma unroll
    for (int o=0;o<16;o++) acc[o]=0.f;
    for (int c=0;c<64;c++){
        const float* zp = z + ((size_t)b*CH + c)*HW;
        #pragma unroll
        for (int t=0;t<9;t++){
            int dy = t/3 - 1, dx = t%3 - 1;
            int yy = y + dy, xv = xx + dx;
            float zv = 0.f;
            if (yy >= 0 && yy < 128 && xv >= 0 && xv < 128) zv = zp[yy*128 + xv];
            const float* w = m1wT + (c*9 + t)*16;
            #pragma unroll
            for (int o=0;o<16;o++) acc[o] = fmaf(w[o], zv, acc[o]);
        }
    }
    #pragma unroll
    for (int o=0;o<16;o++)
        hmid[((size_t)b*16 + o)*HW + p] = fmaxf(acc[o] + m1b[o], 0.f);
}

// ======================================================================
// conv3x3 (16->1), logit out (fp32)
// ======================================================================
__global__ __launch_bounds__(256) void conv2_kernel(
    const float* __restrict__ hmid, const float* __restrict__ m2w, const float* __restrict__ m2b,
    float* __restrict__ logit)
{
    const int idx = blockIdx.x * 256 + threadIdx.x;
    const int b = idx >> 14, p = idx & 16383;
    const int y = p >> 7, xx = p & 127;
    float acc = 0.f;
    for (int c=0;c<16;c++){
        const float* hp = hmid + ((size_t)b*16 + c)*HW;
        #pragma unroll
        for (int t=0;t<9;t++){
            int dy = t/3 - 1, dx = t%3 - 1;
            int yy = y + dy, xv = xx + dx;
            if (yy >= 0 && yy < 128 && xv >= 0 && xv < 128)
                acc = fmaf(m2w[c*9+t], hp[yy*128 + xv], acc);
        }
    }
    logit[idx] = acc + m2b[0];
}

// ======================================================================
extern "C" void kernel_launch(void* const* d_in, const int* in_sizes, int n_in,
                              void* d_out, int out_size, void* d_ws, size_t ws_size,
                              hipStream_t stream)
{
    const float* x    = (const float*)d_in[0];
    const float* g_w  = (const float*)d_in[1];
    const float* g_b  = (const float*)d_in[2];
    const float* th_w = (const float*)d_in[3];
    const float* th_b = (const float*)d_in[4];
    const float* ph_w = (const float*)d_in[5];
    const float* ph_b = (const float*)d_in[6];
    const float* ws_w = (const float*)d_in[7];
    const float* ws_b = (const float*)d_in[8];
    const float* wc_w = (const float*)d_in[9];
    const float* wc_b = (const float*)d_in[10];
    const float* gs   = (const float*)d_in[11];
    const float* gc   = (const float*)d_in[12];
    const float* m1w  = (const float*)d_in[13];
    const float* m1b  = (const float*)d_in[14];
    const float* m2w  = (const float*)d_in[15];
    const float* m2b  = (const float*)d_in[16];

    char* ws = (char*)d_ws;
    u16*   Qb   = (u16*)  (ws + 0);
    u16*   Kb   = (u16*)  (ws + 8388608);
    u16*   Vb   = (u16*)  (ws + 16777216);
    u16*   ysT  = (u16*)  (ws + 25165824);
    u16*   ycb  = (u16*)  (ws + 33554432);
    float* fc   = (float*)(ws + 41943040);
    float* pc   = (float*)(ws + 42991616);
    float* hmid = (float*)(ws + 44040192);
    float* wswT = (float*)(ws + 48234496);
    float* wcwT = (float*)(ws + 48250880);
    float* m1wT = (float*)(ws + 48267264);

    float* logit = (float*)d_out;
    float* zout  = (float*)d_out + 65536;

    prep_kernel<<<36, 256, 0, stream>>>(ws_w, wc_w, m1w, wswT, wcwT, m1wT);
    qkv_kernel<<<dim3(16,32,4), 256, 0, stream>>>(x, th_w, ph_w, g_w, th_b, ph_b, g_b, Qb, Kb, Vb);
    fc_kernel<<<dim3(8,8,4), 256, 0, stream>>>(Qb, Kb, fc);
    softmax_fc_kernel<<<1024, 256, 0, stream>>>(fc, pc);
    yc_kernel<<<dim3(64,4,4), 256, 0, stream>>>(Vb, pc, ycb);
    flash_kernel<<<dim3(128,4), 256, 0, stream>>>(Qb, Kb, Vb, ysT);
    z_kernel<<<dim3(64,2,4), 256, 0, stream>>>(x, ysT, ycb, wswT, wcwT, ws_b, wc_b, gs, gc, zout);
    conv1_kernel<<<dim3(64,4), 256, 0, stream>>>(zout, m1wT, m1b, hmid);
    conv2_kernel<<<256, 256, 0, stream>>>(hmid, m2w, m2b, logit);
}

// Round 4
// 827.325 us; speedup vs baseline: 2.2654x; 2.2654x over previous
//
#include <hip/hip_runtime.h>
#include <stdint.h>

typedef unsigned short u16;
typedef unsigned int   u32;

typedef __attribute__((ext_vector_type(8))) short bf16x8;
typedef __attribute__((ext_vector_type(4))) float f32x4;

// ---------- bf16 helpers (raw ushort representation) ----------
__device__ __forceinline__ float b2f(u16 u) { return __uint_as_float(((u32)u) << 16); }
__device__ __forceinline__ float blo(u32 u) { return __uint_as_float(u << 16); }
__device__ __forceinline__ float bhi(u32 u) { return __uint_as_float(u & 0xffff0000u); }
__device__ __forceinline__ u16 f2b(float f) {
    u32 x = __float_as_uint(f);
    u32 r = (x + 0x7fffu + ((x >> 16) & 1u)) >> 16;
    return (u16)r;
}

#define NB   4
#define IC   256
#define NPOS 4096
#define CH   64
#define HW   16384

// ======================================================================
// prep: transpose small weights (fp32 -> fp32)
// ======================================================================
__global__ __launch_bounds__(256) void prep_kernel(
    const float* __restrict__ wsw, const float* __restrict__ wcw,
    const float* __restrict__ m1w,
    float* __restrict__ wswT, float* __restrict__ wcwT, float* __restrict__ m1wT)
{
    int idx = blockIdx.x * 256 + threadIdx.x;
    if (idx < 4096) {
        int i = idx >> 6, c = idx & 63;
        wswT[i*64 + c] = wsw[c*64 + i];   // [i][c]: per-i rows contiguous
        wcwT[i*64 + c] = wcw[c*64 + i];
    }
    if (idx < 9216) {
        int o = idx & 15, ct = idx >> 4;
        int t = ct % 9, c = ct / 9;
        m1wT[idx] = m1w[(o*64 + c)*9 + t]; // [(c,t)][o]: 16 contiguous per tap
    }
}

// ======================================================================
// QKV: Q/K[n][o], VT[o][n] (bf16 out)
// ======================================================================
__global__ __launch_bounds__(256) void qkv_kernel(
    const float* __restrict__ x,
    const float* __restrict__ thw, const float* __restrict__ phw, const float* __restrict__ gw,
    const float* __restrict__ thb, const float* __restrict__ phb, const float* __restrict__ gb,
    u16* __restrict__ Q, u16* __restrict__ K, u16* __restrict__ VT)
{
    const int n  = blockIdx.x * 256 + threadIdx.x;
    const int ob = blockIdx.y * 8;
    const int b  = blockIdx.z;
    const float* xp = x + (size_t)b * (IC*NPOS) + n;
    float aq[8], ak[8], av[8];
    #pragma unroll
    for (int j=0;j<8;j++){ aq[j]=0.f; ak[j]=0.f; av[j]=0.f; }
    #pragma unroll 4
    for (int i=0;i<256;i++){
        float xv = xp[(size_t)i*NPOS];
        #pragma unroll
        for (int j=0;j<8;j++){
            aq[j] = fmaf(thw[(ob+j)*256 + i], xv, aq[j]);
            ak[j] = fmaf(phw[(ob+j)*256 + i], xv, ak[j]);
            av[j] = fmaf(gw [(ob+j)*256 + i], xv, av[j]);
        }
    }
    size_t base = ((size_t)b*NPOS + n) * IC + ob;
    #pragma unroll
    for (int j=0;j<8;j++){
        Q[base + j] = f2b(aq[j] + thb[ob+j]);
        K[base + j] = f2b(ak[j] + phb[ob+j]);
        VT[((size_t)b*IC + ob + j)*NPOS + n] = f2b(av[j] + gb[ob+j]);
    }
}

// ======================================================================
// f_c[c][d] = sum_n Q[n][c]*K[n][d]   (per batch), fp32 out
// ======================================================================
__global__ __launch_bounds__(256) void fc_kernel(
    const u16* __restrict__ Q, const u16* __restrict__ K, float* __restrict__ fc)
{
    __shared__ __align__(16) u32 Qt[64*16];
    __shared__ __align__(16) u32 Kt[64*16];
    const int tid = threadIdx.x;
    const int c0 = blockIdx.x * 32, d0 = blockIdx.y * 32, b = blockIdx.z;
    const int tc = tid >> 4, td = tid & 15;
    float a00=0.f,a01=0.f,a10=0.f,a11=0.f;
    for (int nt=0; nt<64; nt++){
        int n0 = nt*64;
        __syncthreads();
        {
            int r = tid >> 2, cu = (tid & 3) * 4;
            *(uint4*)&Qt[r*16+cu] = *(const uint4*)(Q + ((size_t)(b*NPOS + n0 + r))*IC + c0 + cu*2);
            *(uint4*)&Kt[r*16+cu] = *(const uint4*)(K + ((size_t)(b*NPOS + n0 + r))*IC + d0 + cu*2);
        }
        __syncthreads();
        #pragma unroll 8
        for (int nn=0; nn<64; nn++){
            u32 qa = Qt[nn*16 + tc];
            u32 ka = Kt[nn*16 + td];
            float q0 = blo(qa), q1 = bhi(qa);
            float k0 = blo(ka), k1 = bhi(ka);
            a00 = fmaf(q0,k0,a00); a01 = fmaf(q0,k1,a01);
            a10 = fmaf(q1,k0,a10); a11 = fmaf(q1,k1,a11);
        }
    }
    float* fo = fc + (size_t)b*65536 + (size_t)(c0 + tc*2)*256 + d0 + td*2;
    fo[0] = a00; fo[1] = a01; fo[256] = a10; fo[257] = a11;
}

// ======================================================================
// row softmax over f_c (rows of 256)
// ======================================================================
__global__ __launch_bounds__(256) void softmax_fc_kernel(
    const float* __restrict__ fc, float* __restrict__ pc)
{
    __shared__ float red[8];
    const int tid = threadIdx.x;
    const int b = blockIdx.x >> 8, c = blockIdx.x & 255;
    float v = fc[(size_t)b*65536 + (size_t)c*256 + tid];
    float m = v;
    #pragma unroll
    for (int d=32; d>=1; d>>=1) m = fmaxf(m, __shfl_xor(m, d));
    if ((tid & 63) == 0) red[tid>>6] = m;
    __syncthreads();
    m = fmaxf(fmaxf(red[0],red[1]), fmaxf(red[2],red[3]));
    float e = __expf(v - m);
    float s = e;
    #pragma unroll
    for (int d=32; d>=1; d>>=1) s += __shfl_xor(s, d);
    if ((tid & 63) == 0) red[4 + (tid>>6)] = s;
    __syncthreads();
    s = red[4]+red[5]+red[6]+red[7];
    pc[(size_t)b*65536 + (size_t)c*256 + tid] = e / s;
}

// ======================================================================
// y_c[n][d] = sum_o V[n][o]*pc[o][d]  (V from VT[o][n]) -> bf16 chw flat
// ======================================================================
__global__ __launch_bounds__(256) void yc_kernel(
    const u16* __restrict__ VT, const float* __restrict__ pc, u16* __restrict__ ycb)
{
    __shared__ __align__(16) u16 Vt_l[32*64];
    __shared__ __align__(16) float Pt[32*64];
    const int tid = threadIdx.x;
    const int n0 = blockIdx.x * 64, d0 = blockIdx.y * 64, b = blockIdx.z;
    const int tn = tid >> 4, td = tid & 15;
    float acc[4][4];
    #pragma unroll
    for (int j=0;j<4;j++)
        #pragma unroll
        for (int d=0;d<4;d++) acc[j][d]=0.f;
    for (int ot=0; ot<8; ot++){
        int o0 = ot*32;
        __syncthreads();
        {
            int ol = tid >> 3, cc = tid & 7;
            *(uint4*)&Vt_l[ol*64 + cc*8] = *(const uint4*)(VT + ((size_t)(b*IC + o0 + ol))*NPOS + n0 + cc*8);
            const float* ps = pc + (size_t)b*65536 + (size_t)(o0 + ol)*256 + d0 + cc*8;
            *(float4*)&Pt[ol*64 + cc*8]     = *(const float4*)ps;
            *(float4*)&Pt[ol*64 + cc*8 + 4] = *(const float4*)(ps + 4);
        }
        __syncthreads();
        #pragma unroll 4
        for (int kk=0; kk<32; kk++){
            float4 pv = *(const float4*)&Pt[kk*64 + td*4];
            uint2 vp = *(const uint2*)&Vt_l[kk*64 + tn*4];
            float v0 = blo(vp.x), v1 = bhi(vp.x), v2 = blo(vp.y), v3 = bhi(vp.y);
            acc[0][0] = fmaf(v0, pv.x, acc[0][0]); acc[0][1] = fmaf(v0, pv.y, acc[0][1]);
            acc[0][2] = fmaf(v0, pv.z, acc[0][2]); acc[0][3] = fmaf(v0, pv.w, acc[0][3]);
            acc[1][0] = fmaf(v1, pv.x, acc[1][0]); acc[1][1] = fmaf(v1, pv.y, acc[1][1]);
            acc[1][2] = fmaf(v1, pv.z, acc[1][2]); acc[1][3] = fmaf(v1, pv.w, acc[1][3]);
            acc[2][0] = fmaf(v2, pv.x, acc[2][0]); acc[2][1] = fmaf(v2, pv.y, acc[2][1]);
            acc[2][2] = fmaf(v2, pv.z, acc[2][2]); acc[2][3] = fmaf(v2, pv.w, acc[2][3]);
            acc[3][0] = fmaf(v3, pv.x, acc[3][0]); acc[3][1] = fmaf(v3, pv.y, acc[3][1]);
            acc[3][2] = fmaf(v3, pv.z, acc[3][2]); acc[3][3] = fmaf(v3, pv.w, acc[3][3]);
        }
    }
    #pragma unroll
    for (int j=0;j<4;j++){
        u32 lo = (u32)f2b(acc[j][0]) | ((u32)f2b(acc[j][1]) << 16);
        u32 hi = (u32)f2b(acc[j][2]) | ((u32)f2b(acc[j][3]) << 16);
        *(uint2*)&ycb[((size_t)b*NPOS + n0 + tn*4 + j)*IC + d0 + td*4] = make_uint2(lo,hi);
    }
}

// ======================================================================
// MFMA flash attention: O = softmax(Q K^T) V, output transposed to
// ysT[b][o][n]. Bq=64 (4 waves x 16 rows), Bk=64, D=256.
// ======================================================================
__global__ __launch_bounds__(256) void flash_mfma_kernel(
    const u16* __restrict__ Q, const u16* __restrict__ K, const u16* __restrict__ VT,
    u16* __restrict__ ysT)
{
    __shared__ __align__(16) u32 Kt[8192];   // 32 KB: K tile (swizzled) + wave-private P/O zones
    __shared__ __align__(16) u32 Vt[8192];   // 32 KB: V^T tile (swizzled)
    const int tid  = threadIdx.x;
    const int w    = tid >> 6;
    const int lane = tid & 63;
    const int q4   = lane >> 4;
    const int l    = lane & 15;
    const int b    = blockIdx.y;
    const int n0   = blockIdx.x * 64;

    // Q fragments (A-layout), held in registers for the whole kernel
    bf16x8 qf[8];
    {
        const u16* qrow = Q + ((size_t)(b*NPOS + n0 + w*16 + l))*IC;
        #pragma unroll
        for (int f=0; f<8; f++)
            qf[f] = *(const bf16x8*)(qrow + f*32 + q4*8);
    }

    f32x4 oacc[16];
    #pragma unroll
    for (int t=0;t<16;t++) oacc[t] = (f32x4){0.f,0.f,0.f,0.f};
    float mrow[4], lrow[4];
    #pragma unroll
    for (int r=0;r<4;r++){ mrow[r] = -1e30f; lrow[r] = 0.f; }

    u16* Pz = (u16*)Kt + w*4096;   // wave-private 8KB zone (P matrix / O transpose)

    for (int kt=0; kt<64; kt++){
        const int m0 = kt*64;
        __syncthreads();   // prior S-reads of Kt & PV-reads of Vt/P complete
        // ---- stage K tile: rows m0..m0+63, chunk-swizzled ----
        #pragma unroll
        for (int j=0;j<8;j++){
            int call = w*8 + j;
            int r = call*2 + (lane>>5);
            int c = (lane & 31) ^ (r & 7);
            const u16* g = K + ((size_t)(b*NPOS + m0 + r))*IC + c*8;
            __builtin_amdgcn_global_load_lds(
                (const __attribute__((address_space(1))) u32*)(const void*)g,
                (__attribute__((address_space(3))) u32*)(void*)&Kt[call*256], 16, 0, 0);
        }
        // ---- stage V^T tile: d rows 0..255 x keys m0..m0+63 ----
        #pragma unroll
        for (int j=0;j<8;j++){
            int call = w*8 + j;
            int d = call*8 + (lane>>3);
            int c = (lane & 7) ^ (d & 7);
            const u16* g = VT + ((size_t)(b*IC + d))*NPOS + m0 + c*8;
            __builtin_amdgcn_global_load_lds(
                (const __attribute__((address_space(1))) u32*)(const void*)g,
                (__attribute__((address_space(3))) u32*)(void*)&Vt[call*256], 16, 0, 0);
        }
        __syncthreads();   // staging complete

        // ---- S = Q K^T  (4 key-tiles of 16, 8 k-steps of 32) ----
        f32x4 sac[4];
        #pragma unroll
        for (int t=0;t<4;t++) sac[t] = (f32x4){0.f,0.f,0.f,0.f};
        #pragma unroll
        for (int f=0; f<8; f++){
            #pragma unroll
            for (int t=0;t<4;t++){
                int r = t*16 + l;
                int c = (f*4 + q4) ^ (r & 7);
                bf16x8 kf = *(const bf16x8*)((const u16*)Kt + r*256 + c*8);
                sac[t] = __builtin_amdgcn_mfma_f32_16x16x32_bf16(qf[f], kf, sac[t], 0, 0, 0);
            }
        }
        __syncthreads();   // all Kt reads done before P zones overwrite Kt

        // ---- online softmax (C-layout row = q4*4+reg) + P write ----
        #pragma unroll
        for (int reg=0; reg<4; reg++){
            float rm = fmaxf(fmaxf(sac[0][reg], sac[1][reg]), fmaxf(sac[2][reg], sac[3][reg]));
            rm = fmaxf(rm, __shfl_xor(rm, 1));
            rm = fmaxf(rm, __shfl_xor(rm, 2));
            rm = fmaxf(rm, __shfl_xor(rm, 4));
            rm = fmaxf(rm, __shfl_xor(rm, 8));
            float mnew  = fmaxf(mrow[reg], rm);
            float alpha = __expf(mrow[reg] - mnew);
            mrow[reg] = mnew;
            float p0 = __expf(sac[0][reg]-mnew), p1 = __expf(sac[1][reg]-mnew);
            float p2 = __expf(sac[2][reg]-mnew), p3 = __expf(sac[3][reg]-mnew);
            float rs = p0+p1+p2+p3;
            rs += __shfl_xor(rs, 1); rs += __shfl_xor(rs, 2);
            rs += __shfl_xor(rs, 4); rs += __shfl_xor(rs, 8);
            lrow[reg] = lrow[reg]*alpha + rs;
            int m = q4*4 + reg;
            Pz[m*72 + l]      = f2b(p0);
            Pz[m*72 + 16 + l] = f2b(p1);
            Pz[m*72 + 32 + l] = f2b(p2);
            Pz[m*72 + 48 + l] = f2b(p3);
            #pragma unroll
            for (int t=0;t<16;t++) oacc[t][reg] *= alpha;
        }

        // ---- O += P V  (16 d-tiles, 2 k-steps of 32) ----
        #pragma unroll
        for (int s=0; s<2; s++){
            bf16x8 pa = *(const bf16x8*)(Pz + l*72 + s*32 + q4*8);
            #pragma unroll
            for (int t=0;t<16;t++){
                int d = t*16 + l;
                int c = (s*4 + q4) ^ (d & 7);
                bf16x8 vb = *(const bf16x8*)((const u16*)Vt + d*64 + c*8);
                oacc[t] = __builtin_amdgcn_mfma_f32_16x16x32_bf16(pa, vb, oacc[t], 0, 0, 0);
            }
        }
    }

    // ---- epilogue: normalize, transpose via wave-private LDS, store ----
    float inv[4];
    #pragma unroll
    for (int reg=0;reg<4;reg++) inv[reg] = 1.f / lrow[reg];
    __syncthreads();
    #pragma unroll
    for (int t=0;t<16;t++)
        #pragma unroll
        for (int reg=0;reg<4;reg++)
            Pz[(t*16 + l)*16 + q4*4 + reg] = f2b(oacc[t][reg] * inv[reg]);
    u16* dst = ysT + (size_t)b*(IC*NPOS) + n0 + w*16;
    for (int p=0; p<32; p++){
        int d = p*8 + (lane>>3);
        u32 val = *(const u32*)(Pz + d*16 + (lane&7)*2);
        *(u32*)(dst + (size_t)d*NPOS + (lane&7)*2) = val;
    }
}

// ======================================================================
// z = x + gs*(Ws@y_s + Ws_b) + gc*(Wc@y_c + Wc_b)   (fp32 out to d_out)
// ======================================================================
__global__ __launch_bounds__(256) void z_kernel(
    const float* __restrict__ x, const u16* __restrict__ ysT, const u16* __restrict__ ycb,
    const float* __restrict__ wswT, const float* __restrict__ wcwT,
    const float* __restrict__ wsb, const float* __restrict__ wcb,
    const float* __restrict__ gs, const float* __restrict__ gc,
    float* __restrict__ zout)
{
    __shared__ __align__(16) float Wsl[64*32];
    __shared__ __align__(16) float Wcl[64*32];
    const int tid = threadIdx.x;
    const int p = blockIdx.x * 256 + tid;
    const int cbase = blockIdx.y * 32;
    const int b = blockIdx.z;
    {
        int i = tid >> 2, c8 = (tid & 3) * 8;
        const float* s1 = wswT + i*64 + cbase + c8;
        const float* s2 = wcwT + i*64 + cbase + c8;
        *(float4*)&Wsl[i*32 + c8]     = *(const float4*)s1;
        *(float4*)&Wsl[i*32 + c8 + 4] = *(const float4*)(s1+4);
        *(float4*)&Wcl[i*32 + c8]     = *(const float4*)s2;
        *(float4*)&Wcl[i*32 + c8 + 4] = *(const float4*)(s2+4);
    }
    __syncthreads();
    float as[32], ac[32];
    #pragma unroll
    for (int c=0;c<32;c++){ as[c]=0.f; ac[c]=0.f; }
    const u16* ysp = ysT + (size_t)b*(IC*NPOS) + p;
    const u16* ycp = ycb + (size_t)b*(IC*NPOS) + p;
    for (int i=0;i<64;i++){
        float ysv = b2f(ysp[(size_t)i*HW]);
        float ycv = b2f(ycp[(size_t)i*HW]);
        #pragma unroll
        for (int c=0;c<32;c++){
            as[c] = fmaf(Wsl[i*32+c], ysv, as[c]);
            ac[c] = fmaf(Wcl[i*32+c], ycv, ac[c]);
        }
    }
    float gsv = gs[0], gcv = gc[0];
    #pragma unroll
    for (int c=0;c<32;c++){
        int cg = cbase + c;
        float xv = x[((size_t)b*CH + cg)*HW + p];
        float zv = fmaf(gsv, as[c] + wsb[cg], xv);
        zv = fmaf(gcv, ac[c] + wcb[cg], zv);
        zout[((size_t)b*CH + cg)*HW + p] = zv;
    }
}

// ======================================================================
// conv3x3 (64->16) + ReLU   (reads fp32 z from d_out)
// ======================================================================
__global__ __launch_bounds__(256) void conv1_kernel(
    const float* __restrict__ z, const float* __restrict__ m1wT, const float* __restrict__ m1b,
    float* __restrict__ hmid)
{
    const int tid = threadIdx.x;
    const int p = blockIdx.x * 256 + tid;
    const int b = blockIdx.y;
    const int y = p >> 7, xx = p & 127;
    float acc[16];
    #pragma unroll
    for (int o=0;o<16;o++) acc[o]=0.f;
    for (int c=0;c<64;c++){
        const float* zp = z + ((size_t)b*CH + c)*HW;
        #pragma unroll
        for (int t=0;t<9;t++){
            int dy = t/3 - 1, dx = t%3 - 1;
            int yy = y + dy, xv = xx + dx;
            float zv = 0.f;
            if (yy >= 0 && yy < 128 && xv >= 0 && xv < 128) zv = zp[yy*128 + xv];
            const float* w = m1wT + (c*9 + t)*16;
            #pragma unroll
            for (int o=0;o<16;o++) acc[o] = fmaf(w[o], zv, acc[o]);
        }
    }
    #pragma unroll
    for (int o=0;o<16;o++)
        hmid[((size_t)b*16 + o)*HW + p] = fmaxf(acc[o] + m1b[o], 0.f);
}

// ======================================================================
// conv3x3 (16->1), logit out (fp32)
// ======================================================================
__global__ __launch_bounds__(256) void conv2_kernel(
    const float* __restrict__ hmid, const float* __restrict__ m2w, const float* __restrict__ m2b,
    float* __restrict__ logit)
{
    const int idx = blockIdx.x * 256 + threadIdx.x;
    const int b = idx >> 14, p = idx & 16383;
    const int y = p >> 7, xx = p & 127;
    float acc = 0.f;
    for (int c=0;c<16;c++){
        const float* hp = hmid + ((size_t)b*16 + c)*HW;
        #pragma unroll
        for (int t=0;t<9;t++){
            int dy = t/3 - 1, dx = t%3 - 1;
            int yy = y + dy, xv = xx + dx;
            if (yy >= 0 && yy < 128 && xv >= 0 && xv < 128)
                acc = fmaf(m2w[c*9+t], hp[yy*128 + xv], acc);
        }
    }
    logit[idx] = acc + m2b[0];
}

// ======================================================================
extern "C" void kernel_launch(void* const* d_in, const int* in_sizes, int n_in,
                              void* d_out, int out_size, void* d_ws, size_t ws_size,
                              hipStream_t stream)
{
    const float* x    = (const float*)d_in[0];
    const float* g_w  = (const float*)d_in[1];
    const float* g_b  = (const float*)d_in[2];
    const float* th_w = (const float*)d_in[3];
    const float* th_b = (const float*)d_in[4];
    const float* ph_w = (const float*)d_in[5];
    const float* ph_b = (const float*)d_in[6];
    const float* ws_w = (const float*)d_in[7];
    const float* ws_b = (const float*)d_in[8];
    const float* wc_w = (const float*)d_in[9];
    const float* wc_b = (const float*)d_in[10];
    const float* gs   = (const float*)d_in[11];
    const float* gc   = (const float*)d_in[12];
    const float* m1w  = (const float*)d_in[13];
    const float* m1b  = (const float*)d_in[14];
    const float* m2w  = (const float*)d_in[15];
    const float* m2b  = (const float*)d_in[16];

    char* ws = (char*)d_ws;
    u16*   Qb   = (u16*)  (ws + 0);
    u16*   Kb   = (u16*)  (ws + 8388608);
    u16*   VTb  = (u16*)  (ws + 16777216);
    u16*   ysT  = (u16*)  (ws + 25165824);
    u16*   ycb  = (u16*)  (ws + 33554432);
    float* fc   = (float*)(ws + 41943040);
    float* pc   = (float*)(ws + 42991616);
    float* hmid = (float*)(ws + 44040192);
    float* wswT = (float*)(ws + 48234496);
    float* wcwT = (float*)(ws + 48250880);
    float* m1wT = (float*)(ws + 48267264);

    float* logit = (float*)d_out;
    float* zout  = (float*)d_out + 65536;

    prep_kernel<<<36, 256, 0, stream>>>(ws_w, wc_w, m1w, wswT, wcwT, m1wT);
    qkv_kernel<<<dim3(16,32,4), 256, 0, stream>>>(x, th_w, ph_w, g_w, th_b, ph_b, g_b, Qb, Kb, VTb);
    fc_kernel<<<dim3(8,8,4), 256, 0, stream>>>(Qb, Kb, fc);
    softmax_fc_kernel<<<1024, 256, 0, stream>>>(fc, pc);
    yc_kernel<<<dim3(64,4,4), 256, 0, stream>>>(VTb, pc, ycb);
    flash_mfma_kernel<<<dim3(64,4), 256, 0, stream>>>(Qb, Kb, VTb, ysT);
    z_kernel<<<dim3(64,2,4), 256, 0, stream>>>(x, ysT, ycb, wswT, wcwT, ws_b, wc_b, gs, gc, zout);
    conv1_kernel<<<dim3(64,4), 256, 0, stream>>>(zout, m1wT, m1b, hmid);
    conv2_kernel<<<256, 256, 0, stream>>>(hmid, m2w, m2b, logit);
}